// Round 8
// baseline (798.721 us; speedup 1.0000x reference)
//
#include <hip/hip_runtime.h>
#include <hip/hip_cooperative_groups.h>
#include <math.h>

namespace cg = cooperative_groups;

// Problem constants (fixed by setup_inputs: B=8, n=256, s=256)
#define NCTRL 256          // control points
#define NA    259          // n + 3 (TPS system size)
#define NAUG  261          // + 2 rhs columns
#define APITCH 264         // padded row pitch (floats) for the augmented matrix
#define BATCH 8
#define SGRID 256
#define NB    32           // LU panel width
#define NPAN  9            // 8 full panels + 1 of width 3
#define PPITCH 36          // LDS row pitch: 36*4=144B, 16B-aligned rows
#define NT    320          // solve block threads (5 waves)
#define PY    4            // eval pixels per thread

// ---------------------------------------------------------------------------
// Ministep engine (r6/r7-proven). Thread tid owns row tid in rr[]; one
// barrier per ministep; parity double-buffered publish. NW = waves in block.
// ---------------------------------------------------------------------------
template<int NBC, int NW>
__device__ __forceinline__ void panel_ministeps(
    float (&rr)[NBC], int& org, const int rows,
    const int tid, const int lane, const int wid,
    float (*redrow)[NW][PPITCH], float (*jrow)[PPITCH],
    float (*redv)[NW], int (*redi)[NW], int (*redo_)[NW], int* jorg)
{
  #pragma unroll
  for (int j = 0; j < NBC; ++j){
    const int par = j & 1;
    float bv = (tid >= j && tid < rows) ? fabsf(rr[j]) : -1.0f;
    int bi = tid;
    #pragma unroll
    for (int off = 32; off; off >>= 1){
      float ov = __shfl_xor(bv, off);
      int   oi = __shfl_xor(bi, off);
      if (ov > bv || (ov == bv && oi < bi)){ bv = ov; bi = oi; }
    }
    if (tid == bi){
      redv[par][wid] = bv; redi[par][wid] = bi; redo_[par][wid] = org;
      if (bv >= 0.0f){
        if (NBC == NB){
          #pragma unroll
          for (int q = 0; q < 8; ++q){
            float4 v; v.x=rr[4*q]; v.y=rr[4*q+1]; v.z=rr[4*q+2]; v.w=rr[4*q+3];
            *(float4*)&redrow[par][wid][4*q] = v;
          }
        } else {
          #pragma unroll
          for (int c = 0; c < NBC; ++c) redrow[par][wid][c] = rr[c];
        }
      }
    }
    if (tid == j){
      jorg[par] = org;
      if (NBC == NB){
        #pragma unroll
        for (int q = 0; q < 8; ++q){
          float4 v; v.x=rr[4*q]; v.y=rr[4*q+1]; v.z=rr[4*q+2]; v.w=rr[4*q+3];
          *(float4*)&jrow[par][4*q] = v;
        }
      } else {
        #pragma unroll
        for (int c = 0; c < NBC; ++c) jrow[par][c] = rr[c];
      }
    }
    __syncthreads();
    float gv = redv[par][0]; int gw = 0;
    #pragma unroll
    for (int w = 1; w < NW; ++w){
      if (redv[par][w] > gv ||
          (redv[par][w] == gv && redi[par][w] < redi[par][gw])){
        gv = redv[par][w]; gw = w;
      }
    }
    const int gbi  = redi[par][gw];
    const int gorg = redo_[par][gw];
    float pr[NBC];
    if (NBC == NB){
      #pragma unroll
      for (int q = 0; q < 8; ++q){
        float4 v = *(const float4*)&redrow[par][gw][4*q];
        pr[4*q]=v.x; pr[4*q+1]=v.y; pr[4*q+2]=v.z; pr[4*q+3]=v.w;
      }
    } else {
      #pragma unroll
      for (int c = 0; c < NBC; ++c) pr[c] = redrow[par][gw][c];
    }
    if (gbi != j){
      if (tid == j){
        #pragma unroll
        for (int c = 0; c < NBC; ++c) rr[c] = pr[c];
        org = gorg;
      } else if (tid == gbi){
        #pragma unroll
        for (int c = 0; c < NBC; ++c) rr[c] = jrow[par][c];
        org = jorg[par];
      }
    }
    if (tid > j && tid < rows){
      const float rpiv = 1.0f / pr[j];
      float f = rr[j] * rpiv;
      rr[j] = f;
      #pragma unroll
      for (int c = j+1; c < NBC; ++c) rr[c] = fmaf(-f, pr[c], rr[c]);
    }
  }
}

// ---------------------------------------------------------------------------
// Trailing update for one panel (r7-proven, strides -> NT). Block (b, s<sbp).
// laswp gather -> TRSM -> GEMM; strip 0 also factorizes the NEXT panel from
// its LDS strip (lookahead) and publishes panel+perm to global.
// ---------------------------------------------------------------------------
template<int NBC, int NBCN, bool LOOK>
__device__ __forceinline__ void do_update(
    float* __restrict__ Ab, int* __restrict__ permbuf,
    const int b, const int s, const int p,
    const int tid, const int lane, const int wid,
    float (*pan)[PPITCH], float (*stage)[PPITCH], float (*ustg)[PPITCH],
    int* perm,
    float (*redrow)[5][PPITCH], float (*jrow)[PPITCH],
    float (*redv)[5], int (*redi)[5], int (*redo_)[5], int* jorg)
{
  const int k0   = p*NB;
  const int rows = NA - k0;
  const int ctop = k0 + NBC;
  const int tc   = NAUG - ctop;
  const int sbp  = (tc + 31) >> 5;
  if (s >= sbp) return;                 // whole-block uniform: no barrier hazard
  const int c0   = s*32;
  const int W    = (tc - c0 < 32) ? (tc - c0) : 32;

  for (int i = tid; i < rows; i += NT)
    perm[i] = permbuf[b*(NPAN*NA) + p*NA + i];
  if (NBC == NB){
    for (int idx = tid; idx < rows*8; idx += NT){
      int i = idx >> 3, q = idx & 7;
      *(float4*)&pan[i][4*q] =
        *(const float4*)(Ab + (size_t)(k0+i)*APITCH + k0 + 4*q);
    }
  } else {
    for (int idx = tid; idx < rows*NBC; idx += NT){
      int i = idx / NBC, c = idx - i*NBC;
      pan[i][c] = Ab[(size_t)(k0+i)*APITCH + k0 + c];
    }
  }
  __syncthreads();

  // laswp gather
  for (int idx = tid; idx < rows*W; idx += NT){
    int i = idx / W, c = idx - i*W;
    stage[i][c] = Ab[(size_t)(k0+perm[i])*APITCH + ctop + c0 + c];
  }
  __syncthreads();

  // TRSM: thread-per-column from LDS
  if (tid < W){
    float u[NBC];
    #pragma unroll
    for (int m = 0; m < NBC; ++m) u[m] = stage[m][tid];
    #pragma unroll
    for (int m = 0; m < NBC; ++m){
      #pragma unroll
      for (int jj = m+1; jj < NBC; ++jj)
        u[jj] = fmaf(-pan[jj][m], u[m], u[jj]);
    }
    #pragma unroll
    for (int m = 0; m < NBC; ++m){
      ustg[m][tid] = u[m];
      Ab[(size_t)(k0+m)*APITCH + ctop + c0 + tid] = u[m];
    }
  }
  __syncthreads();

  // GEMM: A22 -= L21 * U12
  const int R = rows - NBC;
  if (R > 0){
    const int rt = (R + 3) >> 2, ct = (W + 3) >> 2;
    for (int t = tid; t < rt*ct; t += NT){
      int tr = t / ct, tcc = t - tr*ct;
      int i0 = tr*4, cc0 = tcc*4;
      const bool full = (cc0 + 4 <= W);
      int ir[4];
      #pragma unroll
      for (int r = 0; r < 4; ++r){
        int i = i0 + r;
        ir[r] = (i < R) ? i : (R - 1);
      }
      float acc[4][4];
      #pragma unroll
      for (int r = 0; r < 4; ++r){
        if (full){
          float4 v = *(const float4*)&stage[NBC + ir[r]][cc0];
          acc[r][0]=v.x; acc[r][1]=v.y; acc[r][2]=v.z; acc[r][3]=v.w;
        } else {
          #pragma unroll
          for (int c = 0; c < 4; ++c)
            acc[r][c] = (cc0 + c < W) ? stage[NBC + ir[r]][cc0 + c] : 0.0f;
        }
      }
      if (NBC == NB){
        #pragma unroll
        for (int mq = 0; mq < NBC/4; ++mq){
          float4 lv[4];
          #pragma unroll
          for (int r = 0; r < 4; ++r)
            lv[r] = *(const float4*)&pan[NBC + ir[r]][4*mq];
          #pragma unroll
          for (int mi = 0; mi < 4; ++mi){
            float4 uv = *(const float4*)&ustg[4*mq + mi][cc0];
            #pragma unroll
            for (int r = 0; r < 4; ++r){
              float l = (mi==0) ? lv[r].x : (mi==1) ? lv[r].y : (mi==2) ? lv[r].z : lv[r].w;
              acc[r][0] = fmaf(-l, uv.x, acc[r][0]);
              acc[r][1] = fmaf(-l, uv.y, acc[r][1]);
              acc[r][2] = fmaf(-l, uv.z, acc[r][2]);
              acc[r][3] = fmaf(-l, uv.w, acc[r][3]);
            }
          }
        }
      } else {
        #pragma unroll
        for (int mi = 0; mi < NBC; ++mi){
          #pragma unroll
          for (int r = 0; r < 4; ++r){
            float l = pan[NBC + ir[r]][mi];
            #pragma unroll
            for (int c = 0; c < 4; ++c)
              acc[r][c] = fmaf(-l, ustg[mi][cc0 + c], acc[r][c]);
          }
        }
      }
      #pragma unroll
      for (int r = 0; r < 4; ++r){
        if (i0 + r < R){
          float* g = Ab + (size_t)(k0 + NBC + i0 + r)*APITCH + ctop + c0 + cc0;
          if (full){
            float4 v; v.x=acc[r][0]; v.y=acc[r][1]; v.z=acc[r][2]; v.w=acc[r][3];
            *(float4*)g = v;
            if (LOOK && s == 0) *(float4*)&stage[NBC + i0 + r][cc0] = v;
          } else {
            #pragma unroll
            for (int c = 0; c < 4; ++c)
              if (cc0 + c < W){
                g[c] = acc[r][c];
                if (LOOK && s == 0) stage[NBC + i0 + r][cc0 + c] = acc[r][c];
              }
          }
        }
      }
    }
  }

  // lookahead: factor next panel from LDS (strip 0 only)
  if (LOOK && s == 0){
    __syncthreads();
    const int k0n   = k0 + NBC;
    const int rowsN = rows - NBC;
    float rr[NBCN];
    int org = tid;
    if (tid < rowsN){
      #pragma unroll
      for (int c = 0; c < NBCN; ++c) rr[c] = stage[NBC + tid][c];
    } else {
      #pragma unroll
      for (int c = 0; c < NBCN; ++c) rr[c] = 0.0f;
    }
    panel_ministeps<NBCN,5>(rr, org, rowsN, tid, lane, wid,
                            redrow, jrow, redv, redi, redo_, jorg);
    if (tid < rowsN){
      #pragma unroll
      for (int c = 0; c < NBCN; ++c) stage[NBC + tid][c] = rr[c];
      permbuf[b*(NPAN*NA) + (p+1)*NA + tid] = org;
    }
    __syncthreads();
    if (NBCN == NB){
      for (int idx = tid; idx < rowsN*8; idx += NT){
        int i = idx >> 3, q = idx & 7;
        *(float4*)(Ab + (size_t)(k0n+i)*APITCH + k0n + 4*q) =
          *(const float4*)&stage[NBC + i][4*q];
      }
    } else {
      for (int idx = tid; idx < rowsN*NBCN; idx += NT){
        int i = idx / NBCN, c = idx - i*NBCN;
        Ab[(size_t)(k0n+i)*APITCH + k0n + c] = stage[NBC + i][c];
      }
    }
  }
}

// ---------------------------------------------------------------------------
// ONE cooperative kernel: build -> panel0 -> 9x(update+lookahead) -> backsub.
// Grid = 64 blocks (8 batches x 8 strips) x 320 threads; every block executes
// the same grid.sync() sequence (11 syncs), no early returns.
// ---------------------------------------------------------------------------
__global__ __launch_bounds__(NT) void solve_coop(const float* __restrict__ src,
                                                 const float* __restrict__ dst,
                                                 float* __restrict__ A,
                                                 float* __restrict__ wv,
                                                 int* __restrict__ permbuf){
  cg::grid_group grid = cg::this_grid();
  const int b = blockIdx.x >> 3;
  const int s = blockIdx.x & 7;
  const int tid  = threadIdx.x;
  const int lane = tid & 63;
  const int wid  = tid >> 6;
  float* Ab = A + (size_t)b*NA*APITCH;

  __shared__ float pan[NA][PPITCH];        // 37.3 KB
  __shared__ float stage[NA][PPITCH];      // 37.3 KB
  __shared__ float ustg[NB][PPITCH];       //  4.6 KB
  __shared__ int   perm[NA];
  __shared__ float redrow[2][5][PPITCH];
  __shared__ float jrow[2][PPITCH];
  __shared__ float redv[2][5];
  __shared__ int   redi[2][5], redo_[2][5], jorg[2];
  __shared__ float sx[NCTRL], sy[NCTRL];
  __shared__ float t2[NA][2], xs[NA][2];
  __shared__ float u11[NB][NB+1];

  // ================= phase 1: build (8 row-strips per batch) =================
  if (tid < NCTRL){
    float2 v = ((const float2*)(src + b*NCTRL*2))[tid];
    sx[tid] = v.x; sy[tid] = v.y;
  }
  __syncthreads();
  {
    const float* db = dst + b*NCTRL*2;
    const int r0 = s*33;
    const int r1 = (r0 + 33 < NA) ? r0 + 33 : NA;
    const int total = (r1 - r0)*APITCH;
    for (int idx = tid; idx < total; idx += NT){
      int r = r0 + idx / APITCH;
      int c = idx % APITCH;
      float v = 0.0f;
      if (r < NCTRL){
        if (c < NCTRL){
          float dx = sx[r] - sx[c];
          float dy = sy[r] - sy[c];
          v = __builtin_amdgcn_sqrtf(fmaf(dx, dx, dy*dy));
        } else if (c == NCTRL)   v = 1.0f;
        else if (c == NCTRL+1)   v = sx[r];
        else if (c == NCTRL+2)   v = sy[r];
        else if (c == NA)        v = db[2*r];
        else if (c == NA+1)      v = db[2*r+1];
      } else if (c < NCTRL){
        v = (r == NCTRL) ? 1.0f : ((r == NCTRL+1) ? sx[c] : sy[c]);
      }
      Ab[(size_t)r*APITCH + c] = v;
    }
  }
  __threadfence();
  grid.sync();                                            // S1

  // ================= phase 2: panel 0 (strip-0 blocks) =================
  if (s == 0){
    for (int idx = tid; idx < NA*8; idx += NT){
      int i = idx >> 3, q = idx & 7;
      *(float4*)&pan[i][4*q] = *(const float4*)(Ab + (size_t)i*APITCH + 4*q);
    }
    __syncthreads();
    float rr[NB];
    int org = tid;
    if (tid < NA){
      #pragma unroll
      for (int q = 0; q < 8; ++q){
        float4 v = *(const float4*)&pan[tid][4*q];
        rr[4*q]=v.x; rr[4*q+1]=v.y; rr[4*q+2]=v.z; rr[4*q+3]=v.w;
      }
    } else {
      #pragma unroll
      for (int c = 0; c < NB; ++c) rr[c] = 0.0f;
    }
    panel_ministeps<NB,5>(rr, org, NA, tid, lane, wid,
                          redrow, jrow, redv, redi, redo_, jorg);
    if (tid < NA){
      #pragma unroll
      for (int q = 0; q < 8; ++q){
        float4 v; v.x=rr[4*q]; v.y=rr[4*q+1]; v.z=rr[4*q+2]; v.w=rr[4*q+3];
        *(float4*)&pan[tid][4*q] = v;
      }
      permbuf[b*(NPAN*NA) + tid] = org;
    }
    __syncthreads();
    for (int idx = tid; idx < NA*8; idx += NT){
      int i = idx >> 3, q = idx & 7;
      *(float4*)(Ab + (size_t)i*APITCH + 4*q) = *(const float4*)&pan[i][4*q];
    }
  }
  __threadfence();
  grid.sync();                                            // S2

  // ================= phase 3: updates (+ lookahead panels) =================
  #pragma unroll 1
  for (int p = 0; p < 7; ++p){
    do_update<NB,NB,true>(Ab, permbuf, b, s, p, tid, lane, wid,
                          pan, stage, ustg, perm, redrow, jrow, redv, redi, redo_, jorg);
    __threadfence();
    grid.sync();                                          // S3..S9
  }
  do_update<NB,3,true>(Ab, permbuf, b, s, 7, tid, lane, wid,
                       pan, stage, ustg, perm, redrow, jrow, redv, redi, redo_, jorg);
  __threadfence();
  grid.sync();                                            // S10
  do_update<3,3,false>(Ab, permbuf, b, s, 8, tid, lane, wid,
                       pan, stage, ustg, perm, redrow, jrow, redv, redi, redo_, jorg);
  __threadfence();
  grid.sync();                                            // S11

  // ================= phase 4: back-substitution (strip-0 blocks) =============
  if (s == 0){
    for (int i = tid; i < NA; i += NT){
      t2[i][0] = Ab[(size_t)i*APITCH + NA];
      t2[i][1] = Ab[(size_t)i*APITCH + NA + 1];
    }
    __syncthreads();
    for (int bp = NPAN-1; bp >= 0; --bp){
      const int k0 = bp*NB;
      const int nb = (NA - k0 < NB) ? (NA - k0) : NB;
      for (int idx = tid; idx < nb*nb; idx += NT){
        int r = idx / nb, c = idx - r*nb;
        u11[r][c] = Ab[(size_t)(k0+r)*APITCH + k0 + c];
      }
      __syncthreads();
      if (wid == 0){
        int j = lane >> 1, ch = lane & 1;
        float tval = (j < nb) ? t2[k0+j][ch] : 0.0f;
        for (int k = nb-1; k >= 0; --k){
          float tk = __shfl(tval, 2*k + ch);
          float xk = tk / u11[k][k];
          if (j <  k) tval = fmaf(-u11[j][k], xk, tval);
          if (j == k) tval = xk;
        }
        if (j < nb) xs[k0+j][ch] = tval;
      }
      __syncthreads();
      if (nb == NB){
        const int q = tid & 7;
        for (int base = 0; base < k0; base += 40){    // 320/8 rows per pass
          const int i = base + (tid >> 3);
          float px = 0.0f, py = 0.0f;
          if (i < k0){
            float4 v = *(const float4*)(Ab + (size_t)i*APITCH + k0 + 4*q);
            px = v.x*xs[k0+4*q+0][0] + v.y*xs[k0+4*q+1][0]
               + v.z*xs[k0+4*q+2][0] + v.w*xs[k0+4*q+3][0];
            py = v.x*xs[k0+4*q+0][1] + v.y*xs[k0+4*q+1][1]
               + v.z*xs[k0+4*q+2][1] + v.w*xs[k0+4*q+3][1];
          }
          px += __shfl_xor(px, 1); px += __shfl_xor(px, 2); px += __shfl_xor(px, 4);
          py += __shfl_xor(py, 1); py += __shfl_xor(py, 2); py += __shfl_xor(py, 4);
          if (q == 0 && i < k0){
            t2[i][0] -= px;
            t2[i][1] -= py;
          }
        }
      } else {
        for (int i = tid; i < k0; i += NT){
          float s0 = 0.0f, s1 = 0.0f;
          #pragma unroll
          for (int m = 0; m < 3; ++m){
            float u = Ab[(size_t)i*APITCH + k0 + m];
            s0 = fmaf(u, xs[k0+m][0], s0);
            s1 = fmaf(u, xs[k0+m][1], s1);
          }
          t2[i][0] -= s0;
          t2[i][1] -= s1;
        }
      }
      __syncthreads();
    }
    for (int i = tid; i < NA; i += NT){
      wv[((size_t)b*NA + i)*2 + 0] = xs[i][0];
      wv[((size_t)b*NA + i)*2 + 1] = xs[i][1];
    }
  }
}

// ---------------------------------------------------------------------------
// Kernel 3: evaluate the warp. PY pixels (same column) per thread: dx^2
// hoisted, one ds_read_b128 per ctrl point, raw v_sqrt_f32.
// ---------------------------------------------------------------------------
__global__ __launch_bounds__(256) void eval_kernel(const float* __restrict__ src,
                                                   const float* __restrict__ wv,
                                                   float* __restrict__ out){
  const int b  = blockIdx.x >> 6;          // 8 batches x 64 y-groups
  const int yg = blockIdx.x & 63;
  const int xi = threadIdx.x;
  __shared__ float4 cw[NCTRL];             // (sx, sy, wx, wy)
  const float* sb = src + b*NCTRL*2;
  const float* wb = wv + (size_t)b*NA*2;
  {
    float2 sv = ((const float2*)sb)[xi];
    float2 wv2 = ((const float2*)wb)[xi];
    cw[xi] = make_float4(sv.x, sv.y, wv2.x, wv2.y);
  }
  __syncthreads();

  const float step = 2.0f/255.0f;
  const float gx = -1.0f + step*(float)xi;
  const float w0x = wb[512], w1x = wb[514], w2x = wb[516];
  const float w0y = wb[513], w1y = wb[515], w2y = wb[517];

  float gy[PY], ax[PY], ay[PY];
  #pragma unroll
  for (int p = 0; p < PY; ++p){
    gy[p] = -1.0f + step*(float)(yg*PY + p);
    ax[p] = w0x + w1x*gx + w2x*gy[p];
    ay[p] = w0y + w1y*gx + w2y*gy[p];
  }

  #pragma unroll 4
  for (int j = 0; j < NCTRL; ++j){
    float4 c = cw[j];
    float dx = gx - c.x;
    float dx2 = dx*dx;
    #pragma unroll
    for (int p = 0; p < PY; ++p){
      float dy = gy[p] - c.y;
      float r = __builtin_amdgcn_sqrtf(fmaf(dy, dy, dx2));
      ax[p] = fmaf(r, c.z, ax[p]);
      ay[p] = fmaf(r, c.w, ay[p]);
    }
  }

  const int y0 = yg*PY;
  #pragma unroll
  for (int p = 0; p < PY; ++p){
    out[((size_t)(b*2    )*SGRID + y0 + p)*SGRID + xi] = ax[p];
    out[((size_t)(b*2 + 1)*SGRID + y0 + p)*SGRID + xi] = ay[p];
  }
}

// ---------------------------------------------------------------------------
extern "C" void kernel_launch(void* const* d_in, const int* in_sizes, int n_in,
                              void* d_out, int out_size, void* d_ws, size_t ws_size,
                              hipStream_t stream) {
  const float* src = (const float*)d_in[0];
  const float* dst = (const float*)d_in[1];
  float* out = (float*)d_out;

  const size_t matElems = (size_t)BATCH*NA*APITCH;
  float* A     = (float*)d_ws;
  float* wv    = A + matElems;
  int*   permb = (int*)(wv + (size_t)BATCH*NA*2);

  void* args[] = {(void*)&src, (void*)&dst, (void*)&A, (void*)&wv, (void*)&permb};
  hipLaunchCooperativeKernel((void*)solve_coop, dim3(BATCH*8), dim3(NT),
                             args, 0, stream);

  eval_kernel<<<BATCH*(SGRID/PY), 256, 0, stream>>>(src, wv, out);
}